// Round 1
// baseline (1668.766 us; speedup 1.0000x reference)
//
#include <hip/hip_runtime.h>
#include <stdint.h>

#define FF 128

typedef __attribute__((ext_vector_type(8))) short bf8_t;     // 8 x bf16 (4 VGPR) MFMA frag
typedef __attribute__((ext_vector_type(4))) float f4_t;      // MFMA acc
typedef __attribute__((ext_vector_type(8))) uint16_t us8_t;  // 8 x bf16 bits

__device__ __forceinline__ uint16_t f2bf(float f) {
  union { float f; uint32_t u; } v; v.f = f;
  return (uint16_t)((v.u + 0x7fffu + ((v.u >> 16) & 1u)) >> 16);  // RNE
}
__device__ __forceinline__ float bf2f(uint16_t h) {
  union { uint32_t u; float f; } v; v.u = ((uint32_t)h) << 16;
  return v.f;
}

// ---------------- weights f32 -> bf16 ----------------
// layout in wbf: [wsl | w1n | w2n | w1d | w2d] each 128x128, then wgat 128x384
__global__ __launch_bounds__(256) void cvt_w_k(
    const float* __restrict__ wsl, const float* __restrict__ w1n,
    const float* __restrict__ w2n, const float* __restrict__ w1d,
    const float* __restrict__ w2d, const float* __restrict__ wgat,
    uint16_t* __restrict__ o) {
  int i = blockIdx.x * 256 + threadIdx.x;
  const int NW = 5 * 16384;
  if (i >= NW + 49152) return;
  float v;
  if (i < NW) {
    int wsel = i >> 14, j = i & 16383;
    const float* p = (wsel == 0) ? wsl : (wsel == 1) ? w1n : (wsel == 2) ? w2n
                     : (wsel == 3) ? w1d : w2d;
    v = p[j];
  } else {
    v = wgat[i - NW];
  }
  o[i] = f2bf(v);
}

// ---------------- edge scatter: one wave per edge ----------------
__global__ __launch_bounds__(256) void scatter_k(
    const int* __restrict__ src, const int* __restrict__ dst,
    const int* __restrict__ ety, const float* __restrict__ x,
    float* __restrict__ agg_n, float* __restrict__ agg_d, int E) {
  int wid = (blockIdx.x * 256 + threadIdx.x) >> 6;
  int lane = threadIdx.x & 63;
  int nw = (gridDim.x * 256) >> 6;
  for (int e = wid; e < E; e += nw) {
    int s = src[e], d = dst[e], t = ety[e];
    float* agg = t ? agg_d : agg_n;
    const float2 v = ((const float2*)(x + (size_t)s * FF))[lane];
    float* p = agg + (size_t)d * FF + lane * 2;
    unsafeAtomicAdd(p, v.x);
    unsafeAtomicAdd(p + 1, v.y);
  }
}

// D = A @ W^T over K=128 (or a 128-slice of the gate's K=384), 16 rows x 128 cols per wave.
// A frag: lane l -> row l&15, k = (l>>4)*8 + e. B frag: col l&15, same k (contiguous 16B).
__device__ __forceinline__ void mm16(const uint16_t* __restrict__ W, int ld,
                                     const bf8_t* af, f4_t* acc, int lr, int lg) {
#pragma unroll
  for (int s = 0; s < 4; ++s) {
    const int k0 = s * 32 + lg * 8;
#pragma unroll
    for (int t = 0; t < 8; ++t) {
      bf8_t b = *(const bf8_t*)(W + (size_t)(t * 16 + lr) * ld + k0);
      acc[t] = __builtin_amdgcn_mfma_f32_16x16x32_bf16(af[s], b, acc[t], 0, 0, 0);
    }
  }
}

// ---------------- stage 1: x@wsl.T ; (x+agg)@w1.T for both branches + BN stats ----------------
__global__ __launch_bounds__(256) void gemm1_k(
    const float* __restrict__ x, const float* __restrict__ agg_n,
    const float* __restrict__ agg_d, const uint16_t* __restrict__ wbf,
    const float* __restrict__ b_sl, const float* __restrict__ b1n,
    const float* __restrict__ b1d, float* __restrict__ xnx,
    uint16_t* __restrict__ h1n, uint16_t* __restrict__ h1d,
    float* __restrict__ gstats, int N) {
  __shared__ float sstat[4][4][128];  // [wave][sum_n,ss_n,sum_d,ss_d][col]
  const int tid = threadIdx.x;
  const int lane = tid & 63, w = tid >> 6;
  const int lr = lane & 15, lg = lane >> 4;
  const int rowbase = blockIdx.x * 64 + w * 16;
  const int arow = min(rowbase + lr, N - 1);
  const float* xr = x + (size_t)arow * FF;

  f4_t xf[4][2];
#pragma unroll
  for (int s = 0; s < 4; ++s) {
    const int k0 = s * 32 + lg * 8;
    xf[s][0] = *(const f4_t*)(xr + k0);
    xf[s][1] = *(const f4_t*)(xr + k0 + 4);
  }

  bf8_t af[4];
  f4_t acc[8];
  const f4_t zz = {0.f, 0.f, 0.f, 0.f};

  // ---- self-loop ----
#pragma unroll
  for (int s = 0; s < 4; ++s)
#pragma unroll
    for (int j = 0; j < 4; ++j) {
      af[s][j] = (short)f2bf(xf[s][0][j]);
      af[s][j + 4] = (short)f2bf(xf[s][1][j]);
    }
#pragma unroll
  for (int t = 0; t < 8; ++t) acc[t] = zz;
  mm16(wbf, FF, af, acc, lr, lg);
#pragma unroll
  for (int t = 0; t < 8; ++t) {
    const int col = t * 16 + lr;
    const float b = b_sl[col];
#pragma unroll
    for (int r = 0; r < 4; ++r) {
      const int row = rowbase + lg * 4 + r;
      if (row < N) xnx[(size_t)row * FF + col] = acc[t][r] + b;
    }
  }

  // ---- branches ----
#pragma unroll 1
  for (int br = 0; br < 2; ++br) {
    const float* ar = (br ? agg_d : agg_n) + (size_t)arow * FF;
    const uint16_t* wp = wbf + (br ? 3 : 1) * 16384;
    const float* bp = br ? b1d : b1n;
    uint16_t* hp = br ? h1d : h1n;
#pragma unroll
    for (int s = 0; s < 4; ++s) {
      const int k0 = s * 32 + lg * 8;
      f4_t a0 = *(const f4_t*)(ar + k0);
      f4_t a1 = *(const f4_t*)(ar + k0 + 4);
#pragma unroll
      for (int j = 0; j < 4; ++j) {
        af[s][j] = (short)f2bf(xf[s][0][j] + a0[j]);
        af[s][j + 4] = (short)f2bf(xf[s][1][j] + a1[j]);
      }
    }
#pragma unroll
    for (int t = 0; t < 8; ++t) acc[t] = zz;
    mm16(wp, FF, af, acc, lr, lg);
#pragma unroll
    for (int t = 0; t < 8; ++t) {
      const int col = t * 16 + lr;
      const float b = bp[col];
      float sum = 0.f, ss = 0.f;
#pragma unroll
      for (int r = 0; r < 4; ++r) {
        const int row = rowbase + lg * 4 + r;
        const float h = acc[t][r] + b;
        if (row < N) {
          hp[(size_t)row * FF + col] = f2bf(h);
          sum += h;
          ss += h * h;
        }
      }
      sum += __shfl_xor(sum, 16, 64);
      sum += __shfl_xor(sum, 32, 64);
      ss += __shfl_xor(ss, 16, 64);
      ss += __shfl_xor(ss, 32, 64);
      if (lane < 16) {
        sstat[w][br * 2 + 0][col] = sum;
        sstat[w][br * 2 + 1][col] = ss;
      }
    }
  }
  __syncthreads();
  // block reduce over waves -> global atomics (512 entries)
  for (int i = tid; i < 512; i += 256) {
    int a = i >> 7, c = i & 127;
    float v = sstat[0][a][c] + sstat[1][a][c] + sstat[2][a][c] + sstat[3][a][c];
    unsafeAtomicAdd(&gstats[i], v);
  }
}

// ---------------- BN finalize: fold into scale/shift ----------------
__global__ void bnfin_k(const float* __restrict__ gstats,
                        const float* __restrict__ gamn, const float* __restrict__ betn,
                        const float* __restrict__ gamd, const float* __restrict__ betd,
                        float* __restrict__ bnp, int N) {
  int i = threadIdx.x;  // 128
  float invN = 1.f / (float)N;
  {
    float mu = gstats[i] * invN;
    float var = gstats[128 + i] * invN - mu * mu;
    float sc = gamn[i] * rsqrtf(var + 1e-5f);
    bnp[i] = sc;
    bnp[128 + i] = betn[i] - mu * sc;
  }
  {
    float mu = gstats[256 + i] * invN;
    float var = gstats[384 + i] * invN - mu * mu;
    float sc = gamd[i] * rsqrtf(var + 1e-5f);
    bnp[256 + i] = sc;
    bnp[384 + i] = betd[i] - mu * sc;
  }
}

// ---------------- stage 2: BN+ReLU, GEMM2 (both branches), gate GEMM, softmax+cumsum, out ----------------
__global__ __launch_bounds__(256) void fuse2_k(
    const uint16_t* __restrict__ h1n, const uint16_t* __restrict__ h1d,
    const float* __restrict__ xnx, const uint16_t* __restrict__ wbf,
    const float* __restrict__ bnp, const float* __restrict__ b2n,
    const float* __restrict__ b2d, const float* __restrict__ bgat,
    float* __restrict__ out, int N) {
  __shared__ float sm[4][2][16][132];  // [wave][xn,xd][row][col] (stride 132: 16B-aligned rows)
  const int tid = threadIdx.x;
  const int lane = tid & 63, w = tid >> 6;
  const int lr = lane & 15, lg = lane >> 4;
  const int rowbase = blockIdx.x * 64 + w * 16;
  const int arow = min(rowbase + lr, N - 1);

  const uint16_t* wg = wbf + 5 * 16384;

  bf8_t af[4];
  f4_t acc[8];
  const f4_t zz = {0.f, 0.f, 0.f, 0.f};

  // ---- branches: h2 = relu(bn(h1)) @ w2.T + b2 -> LDS ----
#pragma unroll 1
  for (int br = 0; br < 2; ++br) {
    const uint16_t* hp = br ? h1d : h1n;
    const float* bnb = bnp + br * 256;
    const uint16_t* wp = wbf + (br ? 4 : 2) * 16384;
    const float* bp = br ? b2d : b2n;
#pragma unroll
    for (int s = 0; s < 4; ++s) {
      const int k0 = s * 32 + lg * 8;
      us8_t hv = *(const us8_t*)(hp + (size_t)arow * FF + k0);
      f4_t sc0 = *(const f4_t*)(bnb + k0), sc1 = *(const f4_t*)(bnb + k0 + 4);
      f4_t sh0 = *(const f4_t*)(bnb + 128 + k0), sh1 = *(const f4_t*)(bnb + 128 + k0 + 4);
#pragma unroll
      for (int j = 0; j < 4; ++j) {
        af[s][j] = (short)f2bf(fmaxf(bf2f(hv[j]) * sc0[j] + sh0[j], 0.f));
        af[s][j + 4] = (short)f2bf(fmaxf(bf2f(hv[j + 4]) * sc1[j] + sh1[j], 0.f));
      }
    }
#pragma unroll
    for (int t = 0; t < 8; ++t) acc[t] = zz;
    mm16(wp, FF, af, acc, lr, lg);
#pragma unroll
    for (int t = 0; t < 8; ++t) {
      const int col = t * 16 + lr;
      const float b = bp[col];
#pragma unroll
      for (int r = 0; r < 4; ++r) sm[w][br][lg * 4 + r][col] = acc[t][r] + b;
    }
  }
  __syncthreads();

  // ---- gate logits = [xx|xn|xd] @ wgat.T ----
#pragma unroll
  for (int t = 0; t < 8; ++t) acc[t] = zz;
  {
    const float* xr = xnx + (size_t)arow * FF;
#pragma unroll
    for (int s = 0; s < 4; ++s) {
      const int k0 = s * 32 + lg * 8;
      f4_t a0 = *(const f4_t*)(xr + k0), a1 = *(const f4_t*)(xr + k0 + 4);
#pragma unroll
      for (int j = 0; j < 4; ++j) {
        af[s][j] = (short)f2bf(a0[j]);
        af[s][j + 4] = (short)f2bf(a1[j]);
      }
    }
    mm16(wg, 384, af, acc, lr, lg);
  }
#pragma unroll 1
  for (int br = 0; br < 2; ++br) {
#pragma unroll
    for (int s = 0; s < 4; ++s) {
      const int k0 = s * 32 + lg * 8;
      const f4_t a0 = *(const f4_t*)&sm[w][br][lr][k0];
      const f4_t a1 = *(const f4_t*)&sm[w][br][lr][k0 + 4];
#pragma unroll
      for (int j = 0; j < 4; ++j) {
        af[s][j] = (short)f2bf(a0[j]);
        af[s][j + 4] = (short)f2bf(a1[j]);
      }
    }
    mm16(wg + 128 + br * 128, 384, af, acc, lr, lg);
  }

  // ---- per-row softmax + cumsum + output ----
#pragma unroll
  for (int r = 0; r < 4; ++r) {
    float lv[8];
#pragma unroll
    for (int t = 0; t < 8; ++t) lv[t] = acc[t][r] + bgat[t * 16 + lr];
    float m = lv[0];
#pragma unroll
    for (int t = 1; t < 8; ++t) m = fmaxf(m, lv[t]);
#pragma unroll
    for (int d = 1; d < 16; d <<= 1) m = fmaxf(m, __shfl_xor(m, d, 16));
    float g[8];
    float run = 0.f;
#pragma unroll
    for (int t = 0; t < 8; ++t) {
      float p = __expf(lv[t] - m);
      float scn = p;
#pragma unroll
      for (int d = 1; d < 16; d <<= 1) {
        float o = __shfl_up(scn, (unsigned)d, 16);
        if (lr >= d) scn += o;
      }
      g[t] = run + scn;                 // inclusive cumsum (unnormalized)
      run += __shfl(scn, 15, 16);       // tile total
    }
    const float inv = 1.f / run;        // cumsum(softmax) = prefix / total
    const int row = rowbase + lg * 4 + r;
    if (row < N) {
#pragma unroll
      for (int t = 0; t < 8; ++t) {
        const int col = t * 16 + lr;
        const float gat = g[t] * inv;
        const float xx = xnx[(size_t)row * FF + col];
        const float xn = sm[w][0][lg * 4 + r][col];
        const float xdf = sm[w][1][lg * 4 + r][FF - 1 - col];
        // (xx+xn)*(1-g) + (xx+xn+flip(xd))*g  ==  xx + xn + flip(xd)*g
        out[(size_t)row * FF + col] = xx + xn + xdf * gat;
      }
    }
  }
}

extern "C" void kernel_launch(void* const* d_in, const int* in_sizes, int n_in,
                              void* d_out, int out_size, void* d_ws, size_t ws_size,
                              hipStream_t stream) {
  const float* x = (const float*)d_in[0];
  const int* eidx = (const int*)d_in[1];
  const int* etype = (const int*)d_in[2];
  const float* w_sl = (const float*)d_in[3];
  const float* b_sl = (const float*)d_in[4];
  const float* w1n = (const float*)d_in[5];
  const float* b1n = (const float*)d_in[6];
  const float* gamn = (const float*)d_in[7];
  const float* betn = (const float*)d_in[8];
  const float* w2n = (const float*)d_in[9];
  const float* b2n = (const float*)d_in[10];
  const float* w1d = (const float*)d_in[11];
  const float* b1d = (const float*)d_in[12];
  const float* gamd = (const float*)d_in[13];
  const float* betd = (const float*)d_in[14];
  const float* w2d = (const float*)d_in[15];
  const float* b2d = (const float*)d_in[16];
  const float* wgat = (const float*)d_in[17];
  const float* bgat = (const float*)d_in[18];
  float* out = (float*)d_out;

  const int N = in_sizes[0] / FF;
  const int E = in_sizes[2];
  const int* src = eidx;
  const int* dst = eidx + E;

  const size_t NF = (size_t)N * FF;
  float* agg_n = (float*)d_ws;
  float* agg_d = agg_n + NF;
  float* xnx = agg_d + NF;
  uint16_t* h1n = (uint16_t*)(xnx + NF);
  uint16_t* h1d = h1n + NF;
  float* gstats = (float*)(h1d + NF);
  float* bnp = gstats + 512;
  uint16_t* wbf = (uint16_t*)(bnp + 512);

  hipMemsetAsync(agg_n, 0, 2 * NF * sizeof(float), stream);
  hipMemsetAsync(gstats, 0, 512 * sizeof(float), stream);
  cvt_w_k<<<512, 256, 0, stream>>>(w_sl, w1n, w2n, w1d, w2d, wgat, wbf);
  scatter_k<<<2048, 256, 0, stream>>>(src, dst, etype, x, agg_n, agg_d, E);
  const int nb = (N + 63) / 64;
  gemm1_k<<<nb, 256, 0, stream>>>(x, agg_n, agg_d, wbf, b_sl, b1n, b1d, xnx, h1n,
                                  h1d, gstats, N);
  bnfin_k<<<1, 128, 0, stream>>>(gstats, gamn, betn, gamd, betd, bnp, N);
  fuse2_k<<<nb, 256, 0, stream>>>(h1n, h1d, xnx, wbf, bnp, b2n, b2d, bgat, out, N);
}

// Round 2
// 673.651 us; speedup vs baseline: 2.4772x; 2.4772x over previous
//
#include <hip/hip_runtime.h>
#include <stdint.h>

#define FF 128

typedef __attribute__((ext_vector_type(8))) short bf8_t;     // 8 x bf16 (4 VGPR) MFMA frag
typedef __attribute__((ext_vector_type(4))) float f4_t;      // MFMA acc
typedef __attribute__((ext_vector_type(8))) uint16_t us8_t;  // 8 x bf16 bits

__device__ __forceinline__ uint16_t f2bf(float f) {
  union { float f; uint32_t u; } v; v.f = f;
  return (uint16_t)((v.u + 0x7fffu + ((v.u >> 16) & 1u)) >> 16);  // RNE
}
__device__ __forceinline__ float bf2f(uint16_t h) {
  union { uint32_t u; float f; } v; v.u = ((uint32_t)h) << 16;
  return v.f;
}

// ---------------- weights f32 -> bf16 ----------------
__global__ __launch_bounds__(256) void cvt_w_k(
    const float* __restrict__ wsl, const float* __restrict__ w1n,
    const float* __restrict__ w2n, const float* __restrict__ w1d,
    const float* __restrict__ w2d, const float* __restrict__ wgat,
    uint16_t* __restrict__ o) {
  int i = blockIdx.x * 256 + threadIdx.x;
  const int NW = 5 * 16384;
  if (i >= NW + 49152) return;
  float v;
  if (i < NW) {
    int wsel = i >> 14, j = i & 16383;
    const float* p = (wsel == 0) ? wsl : (wsel == 1) ? w1n : (wsel == 2) ? w2n
                     : (wsel == 3) ? w1d : w2d;
    v = p[j];
  } else {
    v = wgat[i - NW];
  }
  o[i] = f2bf(v);
}

// ---------------- counting sort of edges by key = dst*2 + type ----------------
__global__ __launch_bounds__(256) void hist_k(const int* __restrict__ dst,
                                              const int* __restrict__ ety,
                                              int* __restrict__ hist, int E) {
  int i = blockIdx.x * 256 + threadIdx.x;
  if (i < E) atomicAdd(&hist[(dst[i] << 1) | ety[i]], 1);
}

__global__ __launch_bounds__(256) void scan1_k(const int* __restrict__ hist,
                                               int* __restrict__ off,
                                               int* __restrict__ bsum, int nbins) {
  int i = blockIdx.x * 256 + threadIdx.x;
  int v = (i < nbins) ? hist[i] : 0;
  int lane = threadIdx.x & 63, w = threadIdx.x >> 6;
  int s = v;
#pragma unroll
  for (int d = 1; d < 64; d <<= 1) {
    int o = __shfl_up(s, (unsigned)d, 64);
    if (lane >= d) s += o;
  }
  __shared__ int wsum[4];
  if (lane == 63) wsum[w] = s;
  __syncthreads();
  int add = 0;
  for (int k = 0; k < w; ++k) add += wsum[k];
  s += add;
  if (i < nbins) off[i] = s - v;  // exclusive
  if (threadIdx.x == 255) bsum[blockIdx.x] = s;
}

__global__ __launch_bounds__(1024) void scan2_k(int* __restrict__ bsum, int nb) {
  int t = threadIdx.x;
  int v = (t < nb) ? bsum[t] : 0;
  int lane = t & 63, w = t >> 6;
  int s = v;
#pragma unroll
  for (int d = 1; d < 64; d <<= 1) {
    int o = __shfl_up(s, (unsigned)d, 64);
    if (lane >= d) s += o;
  }
  __shared__ int ws[16];
  if (lane == 63) ws[w] = s;
  __syncthreads();
  int add = 0;
  for (int k = 0; k < w; ++k) add += ws[k];
  s += add;
  if (t < nb) bsum[t] = s - v;  // exclusive block offsets
}

__global__ __launch_bounds__(256) void scan3_k(int* __restrict__ off,
                                               int* __restrict__ cur,
                                               const int* __restrict__ bsum,
                                               int nbins, int E) {
  int i = blockIdx.x * 256 + threadIdx.x;
  if (i < nbins) {
    int v = off[i] + bsum[blockIdx.x];
    off[i] = v;
    cur[i] = v;
  }
  if (i == nbins) off[i] = E;
}

__global__ __launch_bounds__(256) void sctidx_k(const int* __restrict__ src,
                                                const int* __restrict__ dst,
                                                const int* __restrict__ ety,
                                                int* __restrict__ cur,
                                                int* __restrict__ ssrc, int E) {
  int i = blockIdx.x * 256 + threadIdx.x;
  if (i < E) {
    int pos = atomicAdd(&cur[(dst[i] << 1) | ety[i]], 1);
    ssrc[pos] = src[i];
  }
}

// ---------------- segment-sum: one wave per (node, relation) ----------------
__global__ __launch_bounds__(256) void agg_k(const int* __restrict__ off,
                                             const int* __restrict__ ssrc,
                                             const float* __restrict__ x,
                                             float* __restrict__ agg_n,
                                             float* __restrict__ agg_d, int nbins) {
  int wid = (blockIdx.x * 256 + threadIdx.x) >> 6;
  int lane = threadIdx.x & 63;
  if (wid >= nbins) return;
  int e = off[wid], end = off[wid + 1];
  float ax = 0.f, ay = 0.f;
  int s_next = (e < end) ? ssrc[e] : 0;
  while (e < end) {
    int s = s_next;
    ++e;
    if (e < end) s_next = ssrc[e];
    float2 v = ((const float2*)(x + (size_t)s * FF))[lane];
    ax += v.x;
    ay += v.y;
  }
  float* agg = (wid & 1) ? agg_d : agg_n;
  float2 o;
  o.x = ax;
  o.y = ay;
  ((float2*)(agg + (size_t)(wid >> 1) * FF))[lane] = o;
}

// D = A @ W^T over K=128 (or a 128-slice of the gate's K=384), 16 rows x 128 cols per wave.
__device__ __forceinline__ void mm16(const uint16_t* __restrict__ W, int ld,
                                     const bf8_t* af, f4_t* acc, int lr, int lg) {
#pragma unroll
  for (int s = 0; s < 4; ++s) {
    const int k0 = s * 32 + lg * 8;
#pragma unroll
    for (int t = 0; t < 8; ++t) {
      bf8_t b = *(const bf8_t*)(W + (size_t)(t * 16 + lr) * ld + k0);
      acc[t] = __builtin_amdgcn_mfma_f32_16x16x32_bf16(af[s], b, acc[t], 0, 0, 0);
    }
  }
}

// ---------------- stage 1: x@wsl.T ; (x+agg)@w1.T for both branches + BN stats ----------------
__global__ __launch_bounds__(256) void gemm1_k(
    const float* __restrict__ x, const float* __restrict__ agg_n,
    const float* __restrict__ agg_d, const uint16_t* __restrict__ wbf,
    const float* __restrict__ b_sl, const float* __restrict__ b1n,
    const float* __restrict__ b1d, float* __restrict__ xnx,
    uint16_t* __restrict__ h1n, uint16_t* __restrict__ h1d,
    float* __restrict__ gstats, int N) {
  __shared__ float sstat[4][4][128];  // [wave][sum_n,ss_n,sum_d,ss_d][col]
  const int tid = threadIdx.x;
  const int lane = tid & 63, w = tid >> 6;
  const int lr = lane & 15, lg = lane >> 4;
  const int rowbase = blockIdx.x * 64 + w * 16;
  const int arow = min(rowbase + lr, N - 1);
  const float* xr = x + (size_t)arow * FF;

  f4_t xf[4][2];
#pragma unroll
  for (int s = 0; s < 4; ++s) {
    const int k0 = s * 32 + lg * 8;
    xf[s][0] = *(const f4_t*)(xr + k0);
    xf[s][1] = *(const f4_t*)(xr + k0 + 4);
  }

  bf8_t af[4];
  f4_t acc[8];
  const f4_t zz = {0.f, 0.f, 0.f, 0.f};

  // ---- self-loop ----
#pragma unroll
  for (int s = 0; s < 4; ++s)
#pragma unroll
    for (int j = 0; j < 4; ++j) {
      af[s][j] = (short)f2bf(xf[s][0][j]);
      af[s][j + 4] = (short)f2bf(xf[s][1][j]);
    }
#pragma unroll
  for (int t = 0; t < 8; ++t) acc[t] = zz;
  mm16(wbf, FF, af, acc, lr, lg);
#pragma unroll
  for (int t = 0; t < 8; ++t) {
    const int col = t * 16 + lr;
    const float b = b_sl[col];
#pragma unroll
    for (int r = 0; r < 4; ++r) {
      const int row = rowbase + lg * 4 + r;
      if (row < N) xnx[(size_t)row * FF + col] = acc[t][r] + b;
    }
  }

  // ---- branches ----
#pragma unroll 1
  for (int br = 0; br < 2; ++br) {
    const float* ar = (br ? agg_d : agg_n) + (size_t)arow * FF;
    const uint16_t* wp = wbf + (br ? 3 : 1) * 16384;
    const float* bp = br ? b1d : b1n;
    uint16_t* hp = br ? h1d : h1n;
#pragma unroll
    for (int s = 0; s < 4; ++s) {
      const int k0 = s * 32 + lg * 8;
      f4_t a0 = *(const f4_t*)(ar + k0);
      f4_t a1 = *(const f4_t*)(ar + k0 + 4);
#pragma unroll
      for (int j = 0; j < 4; ++j) {
        af[s][j] = (short)f2bf(xf[s][0][j] + a0[j]);
        af[s][j + 4] = (short)f2bf(xf[s][1][j] + a1[j]);
      }
    }
#pragma unroll
    for (int t = 0; t < 8; ++t) acc[t] = zz;
    mm16(wp, FF, af, acc, lr, lg);
#pragma unroll
    for (int t = 0; t < 8; ++t) {
      const int col = t * 16 + lr;
      const float b = bp[col];
      float sum = 0.f, ss = 0.f;
#pragma unroll
      for (int r = 0; r < 4; ++r) {
        const int row = rowbase + lg * 4 + r;
        const float h = acc[t][r] + b;
        if (row < N) {
          hp[(size_t)row * FF + col] = f2bf(h);
          sum += h;
          ss += h * h;
        }
      }
      sum += __shfl_xor(sum, 16, 64);
      sum += __shfl_xor(sum, 32, 64);
      ss += __shfl_xor(ss, 16, 64);
      ss += __shfl_xor(ss, 32, 64);
      if (lane < 16) {
        sstat[w][br * 2 + 0][col] = sum;
        sstat[w][br * 2 + 1][col] = ss;
      }
    }
  }
  __syncthreads();
  for (int i = tid; i < 512; i += 256) {
    int a = i >> 7, c = i & 127;
    float v = sstat[0][a][c] + sstat[1][a][c] + sstat[2][a][c] + sstat[3][a][c];
    unsafeAtomicAdd(&gstats[i], v);
  }
}

// ---------------- BN finalize ----------------
__global__ void bnfin_k(const float* __restrict__ gstats,
                        const float* __restrict__ gamn, const float* __restrict__ betn,
                        const float* __restrict__ gamd, const float* __restrict__ betd,
                        float* __restrict__ bnp, int N) {
  int i = threadIdx.x;  // 128
  float invN = 1.f / (float)N;
  {
    float mu = gstats[i] * invN;
    float var = gstats[128 + i] * invN - mu * mu;
    float sc = gamn[i] * rsqrtf(var + 1e-5f);
    bnp[i] = sc;
    bnp[128 + i] = betn[i] - mu * sc;
  }
  {
    float mu = gstats[256 + i] * invN;
    float var = gstats[384 + i] * invN - mu * mu;
    float sc = gamd[i] * rsqrtf(var + 1e-5f);
    bnp[256 + i] = sc;
    bnp[384 + i] = betd[i] - mu * sc;
  }
}

// ---------------- stage 2: BN+ReLU, GEMM2, gate GEMM, softmax+cumsum, out ----------------
__global__ __launch_bounds__(256) void fuse2_k(
    const uint16_t* __restrict__ h1n, const uint16_t* __restrict__ h1d,
    const float* __restrict__ xnx, const uint16_t* __restrict__ wbf,
    const float* __restrict__ bnp, const float* __restrict__ b2n,
    const float* __restrict__ b2d, const float* __restrict__ bgat,
    float* __restrict__ out, int N) {
  __shared__ float sm[4][2][16][132];
  const int tid = threadIdx.x;
  const int lane = tid & 63, w = tid >> 6;
  const int lr = lane & 15, lg = lane >> 4;
  const int rowbase = blockIdx.x * 64 + w * 16;
  const int arow = min(rowbase + lr, N - 1);

  const uint16_t* wg = wbf + 5 * 16384;

  bf8_t af[4];
  f4_t acc[8];
  const f4_t zz = {0.f, 0.f, 0.f, 0.f};

#pragma unroll 1
  for (int br = 0; br < 2; ++br) {
    const uint16_t* hp = br ? h1d : h1n;
    const float* bnb = bnp + br * 256;
    const uint16_t* wp = wbf + (br ? 4 : 2) * 16384;
    const float* bp = br ? b2d : b2n;
#pragma unroll
    for (int s = 0; s < 4; ++s) {
      const int k0 = s * 32 + lg * 8;
      us8_t hv = *(const us8_t*)(hp + (size_t)arow * FF + k0);
      f4_t sc0 = *(const f4_t*)(bnb + k0), sc1 = *(const f4_t*)(bnb + k0 + 4);
      f4_t sh0 = *(const f4_t*)(bnb + 128 + k0), sh1 = *(const f4_t*)(bnb + 128 + k0 + 4);
#pragma unroll
      for (int j = 0; j < 4; ++j) {
        af[s][j] = (short)f2bf(fmaxf(bf2f(hv[j]) * sc0[j] + sh0[j], 0.f));
        af[s][j + 4] = (short)f2bf(fmaxf(bf2f(hv[j + 4]) * sc1[j] + sh1[j], 0.f));
      }
    }
#pragma unroll
    for (int t = 0; t < 8; ++t) acc[t] = zz;
    mm16(wp, FF, af, acc, lr, lg);
#pragma unroll
    for (int t = 0; t < 8; ++t) {
      const int col = t * 16 + lr;
      const float b = bp[col];
#pragma unroll
      for (int r = 0; r < 4; ++r) sm[w][br][lg * 4 + r][col] = acc[t][r] + b;
    }
  }
  __syncthreads();

#pragma unroll
  for (int t = 0; t < 8; ++t) acc[t] = zz;
  {
    const float* xr = xnx + (size_t)arow * FF;
#pragma unroll
    for (int s = 0; s < 4; ++s) {
      const int k0 = s * 32 + lg * 8;
      f4_t a0 = *(const f4_t*)(xr + k0), a1 = *(const f4_t*)(xr + k0 + 4);
#pragma unroll
      for (int j = 0; j < 4; ++j) {
        af[s][j] = (short)f2bf(a0[j]);
        af[s][j + 4] = (short)f2bf(a1[j]);
      }
    }
    mm16(wg, 384, af, acc, lr, lg);
  }
#pragma unroll 1
  for (int br = 0; br < 2; ++br) {
#pragma unroll
    for (int s = 0; s < 4; ++s) {
      const int k0 = s * 32 + lg * 8;
      const f4_t a0 = *(const f4_t*)&sm[w][br][lr][k0];
      const f4_t a1 = *(const f4_t*)&sm[w][br][lr][k0 + 4];
#pragma unroll
      for (int j = 0; j < 4; ++j) {
        af[s][j] = (short)f2bf(a0[j]);
        af[s][j + 4] = (short)f2bf(a1[j]);
      }
    }
    mm16(wg + 128 + br * 128, 384, af, acc, lr, lg);
  }

#pragma unroll
  for (int r = 0; r < 4; ++r) {
    float lv[8];
#pragma unroll
    for (int t = 0; t < 8; ++t) lv[t] = acc[t][r] + bgat[t * 16 + lr];
    float m = lv[0];
#pragma unroll
    for (int t = 1; t < 8; ++t) m = fmaxf(m, lv[t]);
#pragma unroll
    for (int d = 1; d < 16; d <<= 1) m = fmaxf(m, __shfl_xor(m, d, 16));
    float g[8];
    float run = 0.f;
#pragma unroll
    for (int t = 0; t < 8; ++t) {
      float p = __expf(lv[t] - m);
      float scn = p;
#pragma unroll
      for (int d = 1; d < 16; d <<= 1) {
        float o = __shfl_up(scn, (unsigned)d, 16);
        if (lr >= d) scn += o;
      }
      g[t] = run + scn;
      run += __shfl(scn, 15, 16);
    }
    const float inv = 1.f / run;
    const int row = rowbase + lg * 4 + r;
    if (row < N) {
#pragma unroll
      for (int t = 0; t < 8; ++t) {
        const int col = t * 16 + lr;
        const float gat = g[t] * inv;
        const float xx = xnx[(size_t)row * FF + col];
        const float xn = sm[w][0][lg * 4 + r][col];
        const float xdf = sm[w][1][lg * 4 + r][FF - 1 - col];
        out[(size_t)row * FF + col] = xx + xn + xdf * gat;
      }
    }
  }
}

extern "C" void kernel_launch(void* const* d_in, const int* in_sizes, int n_in,
                              void* d_out, int out_size, void* d_ws, size_t ws_size,
                              hipStream_t stream) {
  const float* x = (const float*)d_in[0];
  const int* eidx = (const int*)d_in[1];
  const int* etype = (const int*)d_in[2];
  const float* w_sl = (const float*)d_in[3];
  const float* b_sl = (const float*)d_in[4];
  const float* w1n = (const float*)d_in[5];
  const float* b1n = (const float*)d_in[6];
  const float* gamn = (const float*)d_in[7];
  const float* betn = (const float*)d_in[8];
  const float* w2n = (const float*)d_in[9];
  const float* b2n = (const float*)d_in[10];
  const float* w1d = (const float*)d_in[11];
  const float* b1d = (const float*)d_in[12];
  const float* gamd = (const float*)d_in[13];
  const float* betd = (const float*)d_in[14];
  const float* w2d = (const float*)d_in[15];
  const float* b2d = (const float*)d_in[16];
  const float* wgat = (const float*)d_in[17];
  const float* bgat = (const float*)d_in[18];
  float* out = (float*)d_out;

  const int N = in_sizes[0] / FF;
  const int E = in_sizes[2];
  const int* src = eidx;
  const int* dst = eidx + E;
  const int nbins = 2 * N;

  const size_t NF = (size_t)N * FF;
  float* agg_n = (float*)d_ws;
  float* agg_d = agg_n + NF;
  float* xnx = agg_d + NF;
  uint16_t* h1n = (uint16_t*)(xnx + NF);
  uint16_t* h1d = h1n + NF;
  float* gstats = (float*)(h1d + NF);
  float* bnp = gstats + 512;
  uint16_t* wbf = (uint16_t*)(bnp + 512);
  int* hist = (int*)(wbf + 5 * 16384 + 49152);
  int* off = hist + nbins;        // nbins+1
  int* cur = off + nbins + 1;     // nbins
  int* bsum = cur + nbins;        // <=1024
  int* ssrc = bsum + 1024;        // E

  const int nb1 = (nbins + 255) / 256;

  hipMemsetAsync(hist, 0, (size_t)nbins * sizeof(int), stream);
  hipMemsetAsync(gstats, 0, 512 * sizeof(float), stream);
  cvt_w_k<<<512, 256, 0, stream>>>(w_sl, w1n, w2n, w1d, w2d, wgat, wbf);

  hist_k<<<(E + 255) / 256, 256, 0, stream>>>(dst, etype, hist, E);
  scan1_k<<<nb1, 256, 0, stream>>>(hist, off, bsum, nbins);
  scan2_k<<<1, 1024, 0, stream>>>(bsum, nb1);
  scan3_k<<<(nbins + 256) / 256, 256, 0, stream>>>(off, cur, bsum, nbins, E);
  sctidx_k<<<(E + 255) / 256, 256, 0, stream>>>(src, dst, etype, cur, ssrc, E);
  agg_k<<<(nbins + 3) / 4, 256, 0, stream>>>(off, ssrc, x, agg_n, agg_d, nbins);

  const int nb = (N + 63) / 64;
  gemm1_k<<<nb, 256, 0, stream>>>(x, agg_n, agg_d, wbf, b_sl, b1n, b1d, xnx, h1n,
                                  h1d, gstats, N);
  bnfin_k<<<1, 128, 0, stream>>>(gstats, gamn, betn, gamd, betd, bnp, N);
  fuse2_k<<<nb, 256, 0, stream>>>(h1n, h1d, xnx, wbf, bnp, b2n, b2d, bgat, out, N);
}